// Round 4
// baseline (9470.630 us; speedup 1.0000x reference)
//
#include <hip/hip_runtime.h>

// Problem constants
#define NBATCH 16
#define WEMB   512
#define TLEN   8192
#define KBINS  2048
#define NTROWS (NBATCH * TLEN)                       // 131072
#define XQN    (NBATCH * WEMB * TLEN)                // 67108864
#define XQ_OFF ((size_t)NTROWS)
#define SC_OFF ((size_t)NTROWS + (size_t)XQN)

// Tiling for vq_main
#define MT   64
#define CC   256
#define WB   32
#define NCH  (KBINS / CC)       // 8
#define NWCH (WEMB / WB)        // 16

#define FIX_CAP   32768
#define MARGIN_T  0.25f

// Module-scope scratch; fully rewritten every launch.
__device__ float  g_k2[KBINS];
__device__ double g_fitp[NTROWS / MT];
__device__ double g_pnp[2 * 2048];
__device__ int    g_idx[NTROWS];
__device__ int    g_list[FIX_CAP];
__device__ int    g_nfix;

__global__ void zero_kernel() { g_nfix = 0; }

// ---------------------------------------------------------------- k2[c] = sum_w k[c][w]^2
__global__ __launch_bounds__(256) void k2_kernel(const float* __restrict__ k) {
  const int c = blockIdx.x * 4 + (threadIdx.x >> 6);
  const int lane = threadIdx.x & 63;
  const float4* kr = (const float4*)(k + (size_t)c * WEMB);
  float s = 0.f;
#pragma unroll
  for (int i = 0; i < 2; ++i) {
    float4 v = kr[lane + 64 * i];
    s += v.x * v.x + v.y * v.y + v.z * v.z + v.w * v.w;
  }
#pragma unroll
  for (int m = 1; m < 64; m <<= 1) s += __shfl_xor(s, m);
  if (lane == 0) g_k2[c] = s;
}

// ---------------------------------------------------------------- sum / sumsq of x (prenorm)
__global__ __launch_bounds__(256) void pn_kernel(const float* __restrict__ x) {
  const float4* x4 = (const float4*)x;
  const int stride = gridDim.x * blockDim.x;
  double s = 0.0, s2 = 0.0;
  for (int i = blockIdx.x * blockDim.x + threadIdx.x; i < XQN / 4; i += stride) {
    float4 v = x4[i];
    s  += (double)v.x + (double)v.y + (double)v.z + (double)v.w;
    s2 += (double)v.x * v.x + (double)v.y * v.y + (double)v.z * v.z + (double)v.w * v.w;
  }
#pragma unroll
  for (int m = 1; m < 64; m <<= 1) { s += __shfl_xor(s, m); s2 += __shfl_xor(s2, m); }
  __shared__ double red[8];
  const int wv = threadIdx.x >> 6, lane = threadIdx.x & 63;
  if (lane == 0) { red[wv] = s; red[4 + wv] = s2; }
  __syncthreads();
  if (threadIdx.x == 0) {
    g_pnp[2 * blockIdx.x]     = red[0] + red[1] + red[2] + red[3];
    g_pnp[2 * blockIdx.x + 1] = red[4] + red[5] + red[6] + red[7];
  }
}

// ---------------------------------------------------------------- main VQ kernel (f32, top-2)
template <bool DO_X2>
__device__ __forceinline__ void compute_stage(const float (*xs)[68], const float4* ks4,
                                              int cg, int r0, float acc[8][8], float x2a[8]) {
#pragma unroll 2
  for (int w4 = 0; w4 < WB / 4; ++w4) {
    float4 kv[8];
#pragma unroll
    for (int i = 0; i < 8; ++i) kv[i] = ks4[(cg + 32 * i) * 9 + w4];
#pragma unroll
    for (int j = 0; j < 4; ++j) {
      const int w = 4 * w4 + j;
      float4 a = *(const float4*)&xs[w][r0];
      float4 b = *(const float4*)&xs[w][r0 + 4];
      float xr[8] = {a.x, a.y, a.z, a.w, b.x, b.y, b.z, b.w};
      if (DO_X2) {
#pragma unroll
        for (int rr = 0; rr < 8; ++rr) x2a[rr] = fmaf(xr[rr], xr[rr], x2a[rr]);
      }
#pragma unroll
      for (int i = 0; i < 8; ++i) {
        const float kj = (j == 0) ? kv[i].x : (j == 1) ? kv[i].y : (j == 2) ? kv[i].z : kv[i].w;
#pragma unroll
        for (int rr = 0; rr < 8; ++rr) acc[rr][i] = fmaf(xr[rr], kj, acc[rr][i]);
      }
    }
  }
}

__global__ __launch_bounds__(256) void vq_main(const float* __restrict__ x,
                                               const float* __restrict__ k) {
  __shared__ float  xs[WB][68];
  __shared__ float4 ks4[CC * 9];
  __shared__ float  mind[MT];

  const int tile = blockIdx.x;
  const int row0 = tile * MT;
  const int n    = row0 >> 13;
  const int t0   = row0 & (TLEN - 1);
  const int tid  = threadIdx.x;
  const int cg   = tid & 31;
  const int rg   = tid >> 5;
  const int r0   = rg * 8;

  float bd[8], bd2[8], x2a[8]; int bi[8];
#pragma unroll
  for (int i = 0; i < 8; ++i) { bd[i] = 3.4e38f; bd2[i] = 3.4e38f; bi[i] = 0x7FFFFFFF; x2a[i] = 0.f; }

  const int rs  = tid & 63;
  const int wls = tid >> 6;
  const int w4s = tid & 7;
  const int cls = tid >> 3;

  for (int ch = 0; ch < NCH; ++ch) {
    const int cbase = ch * CC;
    float acc[8][8];
#pragma unroll
    for (int i = 0; i < 8; ++i)
#pragma unroll
      for (int j = 0; j < 8; ++j) acc[i][j] = 0.f;

    for (int wc = 0; wc < NWCH; ++wc) {
      const int w0 = wc * WB;
      __syncthreads();
#pragma unroll
      for (int p = 0; p < 8; ++p) {
        const int w = wls + 4 * p;
        xs[w][rs] = x[(size_t)(n * WEMB + w0 + w) * TLEN + (size_t)(t0 + rs)];
      }
#pragma unroll
      for (int p = 0; p < 8; ++p) {
        const int c = cls + 32 * p;
        ks4[c * 9 + w4s] = *(const float4*)&k[(size_t)(cbase + c) * WEMB + (size_t)(w0 + 4 * w4s)];
      }
      __syncthreads();
      if (ch == 0) compute_stage<true>(xs, ks4, cg, r0, acc, x2a);
      else         compute_stage<false>(xs, ks4, cg, r0, acc, x2a);
    }

    float k2c[8];
#pragma unroll
    for (int i = 0; i < 8; ++i) k2c[i] = g_k2[cbase + cg + 32 * i];

#pragma unroll
    for (int rr = 0; rr < 8; ++rr) {
      // in-lane top-2 over 8 codes (ascending index order)
      float cd = 3.4e38f, cd2 = 3.4e38f; int ci = 0x7FFFFFFF;
#pragma unroll
      for (int i = 0; i < 8; ++i) {
        const float d = fmaf(-2.f, acc[rr][i], x2a[rr]) + k2c[i];
        const int c = cbase + cg + 32 * i;
        if (d < cd) { cd2 = cd; cd = d; ci = c; }
        else        { cd2 = fminf(cd2, d); }
      }
      // cross-lane top-2 merge (32 code lanes)
#pragma unroll
      for (int m = 1; m < 32; m <<= 1) {
        const float od  = __shfl_xor(cd, m);
        const float od2 = __shfl_xor(cd2, m);
        const int   oi  = __shfl_xor(ci, m);
        if (od < cd)      { cd2 = fminf(cd, od2); cd = od; ci = oi; }
        else if (od > cd) { cd2 = fminf(cd2, od); }
        else              { cd2 = cd; if (oi < ci) ci = oi; }   // tie: margin 0 → fixup
      }
      // chunk merge
      if (cd < bd[rr])      { bd2[rr] = fminf(bd[rr], cd2); bd[rr] = cd; bi[rr] = ci; }
      else if (cd > bd[rr]) { bd2[rr] = fminf(bd2[rr], cd); }
      else                  { bd2[rr] = bd[rr]; if (ci < bi[rr]) bi[rr] = ci; }
    }
  }

  if (cg == 0) {
#pragma unroll
    for (int rr = 0; rr < 8; ++rr) {
      mind[r0 + rr] = bd[rr];
      g_idx[row0 + r0 + rr] = bi[rr];
      if (bd2[rr] - bd[rr] < MARGIN_T) {
        const int pos = atomicAdd(&g_nfix, 1);
        if (pos < FIX_CAP) g_list[pos] = row0 + r0 + rr;
      }
    }
  }
  __syncthreads();

  if (tid < 64) {
    double s = (double)mind[tid];
#pragma unroll
    for (int m = 1; m < 64; m <<= 1) s += __shfl_xor(s, m);
    if (tid == 0) g_fitp[tile] = s;
  }
}

// ---------------------------------------------------------------- f64 exact argmin fixup
__global__ __launch_bounds__(256) void fix_kernel(const float* __restrict__ x,
                                                  const float* __restrict__ k) {
  __shared__ float xr[WEMB];
  __shared__ double rbd[4];
  __shared__ int    rbi[4];
  const int nfix = g_nfix < FIX_CAP ? g_nfix : FIX_CAP;
  for (int e = blockIdx.x; e < nfix; e += gridDim.x) {
    const int row = g_list[e];
    const int n = row >> 13, t = row & (TLEN - 1);
    for (int w = threadIdx.x; w < WEMB; w += 256)
      xr[w] = x[(size_t)(n * WEMB + w) * TLEN + (size_t)t];
    __syncthreads();
    double bd = 1e300; int bi = 0x7FFFFFFF;
    for (int p = 0; p < 8; ++p) {
      const int c = threadIdx.x + 256 * p;
      const float* kc = k + (size_t)c * WEMB;
      double d = 0.0;
      for (int w = 0; w < WEMB; ++w) {
        const double df = (double)xr[w] - (double)kc[w];
        d += df * df;
      }
      if (d < bd || (d == bd && c < bi)) { bd = d; bi = c; }
    }
#pragma unroll
    for (int m = 1; m < 64; m <<= 1) {
      const double od = __shfl_xor(bd, m);
      const int    oi = __shfl_xor(bi, m);
      if (od < bd || (od == bd && oi < bi)) { bd = od; bi = oi; }
    }
    const int wv = threadIdx.x >> 6, lane = threadIdx.x & 63;
    if (lane == 0) { rbd[wv] = bd; rbi[wv] = bi; }
    __syncthreads();
    if (threadIdx.x == 0) {
      double fb = rbd[0]; int fi = rbi[0];
#pragma unroll
      for (int v = 1; v < 4; ++v)
        if (rbd[v] < fb || (rbd[v] == fb && rbi[v] < fi)) { fb = rbd[v]; fi = rbi[v]; }
      g_idx[row] = fi;
    }
    __syncthreads();
  }
}

// ---------------------------------------------------------------- x_l write (f32)
__global__ __launch_bounds__(256) void xl_kernel(float* __restrict__ out) {
  const int i = blockIdx.x * 256 + threadIdx.x;
  if (i < NTROWS) out[i] = (float)g_idx[i];
}

// ---------------------------------------------------------------- x_q write (f32 gather)
__global__ __launch_bounds__(256) void xq_kernel(const float* __restrict__ k,
                                                 float* __restrict__ out) {
  const int t = blockIdx.x * 256 + threadIdx.x;  // 32
  const int w = blockIdx.y;                       // 512
  const int n = blockIdx.z;                       // 16
  const int idx = g_idx[n * TLEN + t];
  out[XQ_OFF + (size_t)(n * WEMB + w) * TLEN + (size_t)t] = k[(size_t)idx * WEMB + (size_t)w];
}

// ---------------------------------------------------------------- final scalars (f32)
__global__ __launch_bounds__(256) void fin_kernel(float* __restrict__ out) {
  const int tid = threadIdx.x;
  double fs = 0, s = 0, s2 = 0;
  for (int i = tid; i < 2048; i += 256) {
    fs += g_fitp[i];
    s  += g_pnp[2 * i];
    s2 += g_pnp[2 * i + 1];
  }
#pragma unroll
  for (int m = 1; m < 64; m <<= 1) {
    fs += __shfl_xor(fs, m); s += __shfl_xor(s, m); s2 += __shfl_xor(s2, m);
  }
  __shared__ double red[12];
  const int wv = tid >> 6, lane = tid & 63;
  if (lane == 0) { red[wv] = fs; red[4 + wv] = s; red[8 + wv] = s2; }
  __syncthreads();
  if (tid == 0) {
    const double F  = red[0] + red[1] + red[2] + red[3];
    const double S  = red[4] + red[5] + red[6] + red[7];
    const double S2 = red[8] + red[9] + red[10] + red[11];
    const double nel = (double)NTROWS * (double)WEMB;
    const double mean = S / nel;
    double var = S2 / nel - mean * mean;
    if (var < 0) var = 0;
    out[SC_OFF + 0] = (float)(F / nel);      // commit_loss
    out[SC_OFF + 1] = (float)(F / NTROWS);   // fit
    out[SC_OFF + 2] = (float)sqrt(var);      // prenorm
  }
}

extern "C" void kernel_launch(void* const* d_in, const int* in_sizes, int n_in,
                              void* d_out, int out_size, void* d_ws, size_t ws_size,
                              hipStream_t stream) {
  const float* x = (const float*)d_in[0];
  const float* k = (const float*)d_in[1];
  float* out = (float*)d_out;
  (void)d_ws; (void)ws_size; (void)in_sizes; (void)n_in; (void)out_size;

  hipLaunchKernelGGL(zero_kernel, dim3(1), dim3(1), 0, stream);
  hipLaunchKernelGGL(k2_kernel, dim3(KBINS / 4), dim3(256), 0, stream, k);
  hipLaunchKernelGGL(pn_kernel, dim3(2048), dim3(256), 0, stream, x);
  hipLaunchKernelGGL(vq_main, dim3(NTROWS / MT), dim3(256), 0, stream, x, k);
  hipLaunchKernelGGL(fix_kernel, dim3(2048), dim3(256), 0, stream, x, k);
  hipLaunchKernelGGL(xl_kernel, dim3(NTROWS / 256), dim3(256), 0, stream, out);
  hipLaunchKernelGGL(xq_kernel, dim3(TLEN / 256, WEMB, NBATCH), dim3(256), 0, stream, k, out);
  hipLaunchKernelGGL(fin_kernel, dim3(1), dim3(256), 0, stream, out);
}

// Round 5
// 2860.739 us; speedup vs baseline: 3.3106x; 3.3106x over previous
//
#include <hip/hip_runtime.h>

// Problem constants
#define NBATCH 16
#define WEMB   512
#define TLEN   8192
#define KBINS  2048
#define NTROWS (NBATCH * TLEN)                       // 131072
#define XQN    (NBATCH * WEMB * TLEN)                // 67108864
#define XQ_OFF ((size_t)NTROWS)
#define SC_OFF ((size_t)NTROWS + (size_t)XQN)

#define FIX_CAP   32768
#define MARGIN_T  0.25f

typedef __attribute__((ext_vector_type(8))) short short8;
typedef __attribute__((ext_vector_type(4))) float f32x4;

// Module-scope scratch; fully rewritten every launch.
__device__ float          g_k2[KBINS];
__device__ double         g_fitp[NTROWS / 256];      // 512
__device__ double         g_pnp[2 * 2048];
__device__ int            g_idx[NTROWS];
__device__ int            g_list[FIX_CAP];
__device__ int            g_nfix;
__device__ unsigned short g_kh[KBINS * WEMB];        // bf16 hi plane of k
__device__ unsigned short g_kl[KBINS * WEMB];        // bf16 lo plane of k
__device__ unsigned short g_xh[(size_t)NTROWS * WEMB]; // bf16 hi, TRANSPOSED [n][t][w]
__device__ unsigned short g_xl[(size_t)NTROWS * WEMB]; // bf16 lo, TRANSPOSED [n][t][w]
__device__ float          g_x2[NTROWS];

static __device__ __forceinline__ unsigned short f2bf(float f) {
  unsigned int u;
  __builtin_memcpy(&u, &f, 4);
  return (unsigned short)((u + 0x7FFFu + ((u >> 16) & 1u)) >> 16);
}
static __device__ __forceinline__ float bf2f(unsigned short h) {
  unsigned int u = ((unsigned int)h) << 16;
  float f;
  __builtin_memcpy(&f, &u, 4);
  return f;
}

// ---------------------------------------------------------------- k2[c] = sum_w k[c][w]^2
__global__ __launch_bounds__(256) void k2_kernel(const float* __restrict__ k) {
  const int c = blockIdx.x * 4 + (threadIdx.x >> 6);
  const int lane = threadIdx.x & 63;
  const float4* kr = (const float4*)(k + (size_t)c * WEMB);
  float s = 0.f;
#pragma unroll
  for (int i = 0; i < 2; ++i) {
    float4 v = kr[lane + 64 * i];
    s += v.x * v.x + v.y * v.y + v.z * v.z + v.w * v.w;
  }
#pragma unroll
  for (int m = 1; m < 64; m <<= 1) s += __shfl_xor(s, m);
  if (lane == 0) g_k2[c] = s;
}

// ---------------------------------------------------------------- k -> bf16 hi/lo planes
__global__ __launch_bounds__(256) void kprep_kernel(const float* __restrict__ k) {
  const int i = blockIdx.x * 256 + threadIdx.x;    // over 262144 float4
  float4 v = ((const float4*)k)[i];
  ushort4 h, l;
  h.x = f2bf(v.x); l.x = f2bf(v.x - bf2f(h.x));
  h.y = f2bf(v.y); l.y = f2bf(v.y - bf2f(h.y));
  h.z = f2bf(v.z); l.z = f2bf(v.z - bf2f(h.z));
  h.w = f2bf(v.w); l.w = f2bf(v.w - bf2f(h.w));
  ((ushort4*)g_kh)[i] = h;
  ((ushort4*)g_kl)[i] = l;
}

// ------------------------------------------- prenorm partials + per-row x2 (f32)
__global__ __launch_bounds__(256) void pnx2_kernel(const float* __restrict__ x) {
  const int b = blockIdx.x;           // 2048
  const int n = b >> 7;
  const int tc = b & 127;
  const int tid = threadIdx.x, lane = tid & 63, wv = tid >> 6;
  const int t = tc * 64 + lane;
  float s2f = 0.f; double s = 0.0, s2 = 0.0;
  const size_t base = ((size_t)n * WEMB) * TLEN + (size_t)t;
  for (int w = wv * 128; w < wv * 128 + 128; ++w) {
    const float v = x[base + (size_t)w * TLEN];
    s2f = fmaf(v, v, s2f);
    s += (double)v; s2 += (double)v * v;
  }
  __shared__ float p[4][64];
  __shared__ double red[8];
  p[wv][lane] = s2f;
#pragma unroll
  for (int m = 1; m < 64; m <<= 1) { s += __shfl_xor(s, m); s2 += __shfl_xor(s2, m); }
  if (lane == 0) { red[wv] = s; red[4 + wv] = s2; }
  __syncthreads();
  if (tid < 64) g_x2[(size_t)n * TLEN + tc * 64 + tid] = p[0][tid] + p[1][tid] + p[2][tid] + p[3][tid];
  if (tid == 0) {
    g_pnp[2 * b]     = red[0] + red[1] + red[2] + red[3];
    g_pnp[2 * b + 1] = red[4] + red[5] + red[6] + red[7];
  }
}

// ------------------------------------------- x -> transposed bf16 hi/lo planes [n][t][w]
__global__ __launch_bounds__(256) void xprep_kernel(const float* __restrict__ x) {
  __shared__ unsigned short sh[64 * 66], sl[64 * 66];
  const int tt = blockIdx.x;   // 128 -> t0
  const int wt = blockIdx.y;   // 8   -> w0
  const int n  = blockIdx.z;   // 16
  const int tid = threadIdx.x;
  const int t0 = tt * 64, w0 = wt * 64;
#pragma unroll
  for (int rep = 0; rep < 16; ++rep) {
    const int task = tid + rep * 256;        // 0..4095
    const int t = task & 63, w = task >> 6;
    const float v = x[((size_t)(n * WEMB + w0 + w)) * TLEN + (size_t)(t0 + t)];
    const unsigned short h = f2bf(v);
    const unsigned short l = f2bf(v - bf2f(h));
    sh[w * 66 + t] = h;
    sl[w * 66 + t] = l;
  }
  __syncthreads();
#pragma unroll
  for (int rep = 0; rep < 16; ++rep) {
    const int task = tid + rep * 256;
    const int w = task & 63, t = task >> 6;
    const size_t o = ((size_t)n * TLEN + (size_t)(t0 + t)) * WEMB + (size_t)(w0 + w);
    g_xh[o] = sh[w * 66 + t];
    g_xl[o] = sl[w * 66 + t];
  }
}

__global__ void zero_kernel() { g_nfix = 0; }

// ---------------------------------------------------------------- MFMA VQ kernel
// 256 rows/block, 16 chunks of 128 codes, BK=32. dist = x2 - 2*(hh+hl+lh) + k2.
__global__ __launch_bounds__(256, 2) void vq_mfma() {
  __shared__ short xh_s[256 * 40];   // rows padded to 80B: conflict-free b128
  __shared__ short xl_s[256 * 40];
  __shared__ short kh_s[128 * 40];
  __shared__ short kl_s[128 * 40];
  __shared__ float x2s[256];
  __shared__ float k2s[128];
  __shared__ float rd1[256], rd2[256];
  __shared__ int   ri1[256];
  __shared__ double redd[4];

  const int tid  = threadIdx.x;
  const int lane = tid & 63, wv = tid >> 6;
  const int g    = lane >> 4, i16 = lane & 15;
  const int wrow0 = wv * 64;
  const int rows0 = blockIdx.x * 256;
  const int n = rows0 >> 13, t0 = rows0 & (TLEN - 1);

  rd1[tid] = 3.4e38f; rd2[tid] = 3.4e38f; ri1[tid] = 0;
  x2s[tid] = g_x2[rows0 + tid];

  for (int cc = 0; cc < 16; ++cc) {
    const int cbase = cc * 128;
    __syncthreads();                       // protect k2s/rd from previous epilogue
    if (tid < 128) k2s[tid] = g_k2[cbase + tid];

    f32x4 acc[4][8];
#pragma unroll
    for (int mt = 0; mt < 4; ++mt)
#pragma unroll
      for (int nt = 0; nt < 8; ++nt) acc[mt][nt] = (f32x4){0.f, 0.f, 0.f, 0.f};

    for (int ks = 0; ks < 16; ++ks) {
      const int w0 = ks * 32;
      __syncthreads();
#pragma unroll
      for (int rep = 0; rep < 4; ++rep) {   // x tiles: 256 t x 4 octets
        const int task = tid + rep * 256;
        const int t = task & 255, oct = task >> 8;
        const size_t src = ((size_t)(n * TLEN + t0 + t)) * WEMB + (size_t)(w0 + oct * 8);
        *(short8*)&xh_s[t * 40 + oct * 8] = *(const short8*)&g_xh[src];
        *(short8*)&xl_s[t * 40 + oct * 8] = *(const short8*)&g_xl[src];
      }
#pragma unroll
      for (int rep = 0; rep < 2; ++rep) {   // k tiles: 128 c x 4 octets
        const int task = tid + rep * 256;
        const int oct = task & 3, c = task >> 2;
        const size_t src = ((size_t)(cbase + c)) * WEMB + (size_t)(w0 + oct * 8);
        *(short8*)&kh_s[c * 40 + oct * 8] = *(const short8*)&g_kh[src];
        *(short8*)&kl_s[c * 40 + oct * 8] = *(const short8*)&g_kl[src];
      }
      __syncthreads();

      short8 ah[4], al[4];
#pragma unroll
      for (int mt = 0; mt < 4; ++mt) {
        const int row = wrow0 + mt * 16 + i16;
        ah[mt] = *(const short8*)&xh_s[row * 40 + g * 8];
        al[mt] = *(const short8*)&xl_s[row * 40 + g * 8];
      }
#pragma unroll
      for (int nt = 0; nt < 8; ++nt) {
        const int c = nt * 16 + i16;
        const short8 bh = *(const short8*)&kh_s[c * 40 + g * 8];
        const short8 bl = *(const short8*)&kl_s[c * 40 + g * 8];
#pragma unroll
        for (int mt = 0; mt < 4; ++mt)
          acc[mt][nt] = __builtin_amdgcn_mfma_f32_16x16x32_bf16(ah[mt], bh, acc[mt][nt], 0, 0, 0);
#pragma unroll
        for (int mt = 0; mt < 4; ++mt)
          acc[mt][nt] = __builtin_amdgcn_mfma_f32_16x16x32_bf16(ah[mt], bl, acc[mt][nt], 0, 0, 0);
#pragma unroll
        for (int mt = 0; mt < 4; ++mt)
          acc[mt][nt] = __builtin_amdgcn_mfma_f32_16x16x32_bf16(al[mt], bh, acc[mt][nt], 0, 0, 0);
      }
    }

    // epilogue: dist + top-2 (D layout: row = g*4 + reg, col = i16)
#pragma unroll
    for (int mt = 0; mt < 4; ++mt) {
#pragma unroll
      for (int r = 0; r < 4; ++r) {
        const int row = wrow0 + mt * 16 + g * 4 + r;
        const float xx = x2s[row];
        float d1 = 3.4e38f, d2 = 3.4e38f; int i1 = 0;
#pragma unroll
        for (int nt = 0; nt < 8; ++nt) {
          const float d = fmaf(-2.f, acc[mt][nt][r], xx) + k2s[nt * 16 + i16];
          const int code = cbase + nt * 16 + i16;
          if (d < d1) { d2 = d1; d1 = d; i1 = code; } else d2 = fminf(d2, d);
        }
#pragma unroll
        for (int m = 1; m < 16; m <<= 1) {
          const float o1 = __shfl_xor(d1, m);
          const float o2 = __shfl_xor(d2, m);
          const int   oi = __shfl_xor(i1, m);
          if (o1 < d1)      { d2 = fminf(d1, o2); d1 = o1; i1 = oi; }
          else if (o1 > d1) { d2 = fminf(d2, o1); }
          else              { d2 = d1; if (oi < i1) i1 = oi; }  // tie -> margin 0 -> fixup
        }
        if (i16 == 0) {
          const float c1 = rd1[row], c2 = rd2[row];
          if (d1 < c1)      { rd1[row] = d1; rd2[row] = fminf(c1, d2); ri1[row] = i1; }
          else if (d1 > c1) { rd2[row] = fminf(c2, d1); }
          else              { rd2[row] = c1; if (i1 < ri1[row]) ri1[row] = i1; }
        }
      }
    }
  }
  __syncthreads();

  const int grow = rows0 + tid;
  g_idx[grow] = ri1[tid];
  if (rd2[tid] - rd1[tid] < MARGIN_T) {
    const int pos = atomicAdd(&g_nfix, 1);
    if (pos < FIX_CAP) g_list[pos] = grow;
  }
  double s = (double)rd1[tid];
#pragma unroll
  for (int m = 1; m < 64; m <<= 1) s += __shfl_xor(s, m);
  if (lane == 0) redd[wv] = s;
  __syncthreads();
  if (tid == 0) g_fitp[blockIdx.x] = redd[0] + redd[1] + redd[2] + redd[3];
}

// ---------------------------------------------------------------- f64 exact argmin fixup
__global__ __launch_bounds__(256) void fix_kernel(const float* __restrict__ x,
                                                  const float* __restrict__ k) {
  __shared__ float xr[WEMB];
  __shared__ double rbd[4];
  __shared__ int    rbi[4];
  const int nfix = g_nfix < FIX_CAP ? g_nfix : FIX_CAP;
  for (int e = blockIdx.x; e < nfix; e += gridDim.x) {
    const int row = g_list[e];
    const int n = row >> 13, t = row & (TLEN - 1);
    for (int w = threadIdx.x; w < WEMB; w += 256)
      xr[w] = x[(size_t)(n * WEMB + w) * TLEN + (size_t)t];
    __syncthreads();
    double bd = 1e300; int bi = 0x7FFFFFFF;
    for (int p = 0; p < 8; ++p) {
      const int c = threadIdx.x + 256 * p;
      const float* kc = k + (size_t)c * WEMB;
      double d = 0.0;
      for (int w = 0; w < WEMB; ++w) {
        const double df = (double)xr[w] - (double)kc[w];
        d += df * df;
      }
      if (d < bd || (d == bd && c < bi)) { bd = d; bi = c; }
    }
#pragma unroll
    for (int m = 1; m < 64; m <<= 1) {
      const double od = __shfl_xor(bd, m);
      const int    oi = __shfl_xor(bi, m);
      if (od < bd || (od == bd && oi < bi)) { bd = od; bi = oi; }
    }
    const int wv = threadIdx.x >> 6, lane = threadIdx.x & 63;
    if (lane == 0) { rbd[wv] = bd; rbi[wv] = bi; }
    __syncthreads();
    if (threadIdx.x == 0) {
      double fb = rbd[0]; int fi = rbi[0];
#pragma unroll
      for (int v = 1; v < 4; ++v)
        if (rbd[v] < fb || (rbd[v] == fb && rbi[v] < fi)) { fb = rbd[v]; fi = rbi[v]; }
      g_idx[row] = fi;
    }
    __syncthreads();
  }
}

// ---------------------------------------------------------------- x_l write (f32)
__global__ __launch_bounds__(256) void xl_kernel(float* __restrict__ out) {
  const int i = blockIdx.x * 256 + threadIdx.x;
  if (i < NTROWS) out[i] = (float)g_idx[i];
}

// ---------------------------------------------------------------- x_q write (f32 gather)
__global__ __launch_bounds__(256) void xq_kernel(const float* __restrict__ k,
                                                 float* __restrict__ out) {
  const int t = blockIdx.x * 256 + threadIdx.x;
  const int w = blockIdx.y;
  const int n = blockIdx.z;
  const int idx = g_idx[n * TLEN + t];
  out[XQ_OFF + (size_t)(n * WEMB + w) * TLEN + (size_t)t] = k[(size_t)idx * WEMB + (size_t)w];
}

// ---------------------------------------------------------------- final scalars (f32)
__global__ __launch_bounds__(256) void fin_kernel(float* __restrict__ out) {
  const int tid = threadIdx.x;
  double fs = 0, s = 0, s2 = 0;
  for (int i = tid; i < 512; i += 256) fs += g_fitp[i];
  for (int i = tid; i < 2048; i += 256) { s += g_pnp[2 * i]; s2 += g_pnp[2 * i + 1]; }
#pragma unroll
  for (int m = 1; m < 64; m <<= 1) {
    fs += __shfl_xor(fs, m); s += __shfl_xor(s, m); s2 += __shfl_xor(s2, m);
  }
  __shared__ double red[12];
  const int wv = tid >> 6, lane = tid & 63;
  if (lane == 0) { red[wv] = fs; red[4 + wv] = s; red[8 + wv] = s2; }
  __syncthreads();
  if (tid == 0) {
    const double F  = red[0] + red[1] + red[2] + red[3];
    const double S  = red[4] + red[5] + red[6] + red[7];
    const double S2 = red[8] + red[9] + red[10] + red[11];
    const double nel = (double)NTROWS * (double)WEMB;
    const double mean = S / nel;
    double var = S2 / nel - mean * mean;
    if (var < 0) var = 0;
    out[SC_OFF + 0] = (float)(F / nel);      // commit_loss
    out[SC_OFF + 1] = (float)(F / NTROWS);   // fit
    out[SC_OFF + 2] = (float)sqrt(var);      // prenorm
  }
}

extern "C" void kernel_launch(void* const* d_in, const int* in_sizes, int n_in,
                              void* d_out, int out_size, void* d_ws, size_t ws_size,
                              hipStream_t stream) {
  const float* x = (const float*)d_in[0];
  const float* k = (const float*)d_in[1];
  float* out = (float*)d_out;
  (void)d_ws; (void)ws_size; (void)in_sizes; (void)n_in; (void)out_size;

  hipLaunchKernelGGL(zero_kernel, dim3(1), dim3(1), 0, stream);
  hipLaunchKernelGGL(k2_kernel, dim3(KBINS / 4), dim3(256), 0, stream, k);
  hipLaunchKernelGGL(kprep_kernel, dim3(1024), dim3(256), 0, stream, k);
  hipLaunchKernelGGL(pnx2_kernel, dim3(2048), dim3(256), 0, stream, x);
  hipLaunchKernelGGL(xprep_kernel, dim3(128, 8, 16), dim3(256), 0, stream, x);
  hipLaunchKernelGGL(vq_mfma, dim3(NTROWS / 256), dim3(256), 0, stream);
  hipLaunchKernelGGL(fix_kernel, dim3(2048), dim3(256), 0, stream, x, k);
  hipLaunchKernelGGL(xl_kernel, dim3(NTROWS / 256), dim3(256), 0, stream, out);
  hipLaunchKernelGGL(xq_kernel, dim3(TLEN / 256, WEMB, NBATCH), dim3(256), 0, stream, k, out);
  hipLaunchKernelGGL(fin_kernel, dim3(1), dim3(256), 0, stream, out);
}

// Round 6
// 2719.022 us; speedup vs baseline: 3.4831x; 1.0521x over previous
//
#include <hip/hip_runtime.h>

// Problem constants
#define NBATCH 16
#define WEMB   512
#define TLEN   8192
#define KBINS  2048
#define NTROWS (NBATCH * TLEN)                       // 131072
#define XQN    (NBATCH * WEMB * TLEN)                // 67108864
#define XQ_OFF ((size_t)NTROWS)
#define SC_OFF ((size_t)NTROWS + (size_t)XQN)

#define FIX_CAP   32768
#define MARGIN_T  0.25f

// vq_mfma tiling: 64 rows/block, x LDS-resident, 4 chunks x 512 codes, 8 waves
#define R         64
#define ROWSTRIDE 1032          // shorts per row: [ks16][plane2][w32] + 8 pad (516 words = 4 mod 32)
#define CHUNK     512
#define NCHK      4
#define CPW       64            // codes per wave

typedef __attribute__((ext_vector_type(8))) short short8;
typedef __attribute__((ext_vector_type(4))) float f32x4;

// Module-scope scratch; fully rewritten every launch.
__device__ float          g_k2[KBINS];
__device__ double         g_fitp[NTROWS / R];        // 2048
__device__ double         g_pnp[2 * 2048];
__device__ int            g_idx[NTROWS];
__device__ int            g_list[FIX_CAP];
__device__ int            g_nfix;
__device__ unsigned short g_kh[KBINS * WEMB];        // bf16 hi plane of k
__device__ unsigned short g_kl[KBINS * WEMB];        // bf16 lo plane of k

static __device__ __forceinline__ unsigned short f2bf(float f) {
  unsigned int u;
  __builtin_memcpy(&u, &f, 4);
  return (unsigned short)((u + 0x7FFFu + ((u >> 16) & 1u)) >> 16);
}
static __device__ __forceinline__ float bf2f(unsigned short h) {
  unsigned int u = ((unsigned int)h) << 16;
  float f;
  __builtin_memcpy(&f, &u, 4);
  return f;
}

__global__ void zero_kernel() { g_nfix = 0; }

// ---------------------------------------------------------------- k2[c] = sum_w k[c][w]^2
__global__ __launch_bounds__(256) void k2_kernel(const float* __restrict__ k) {
  const int c = blockIdx.x * 4 + (threadIdx.x >> 6);
  const int lane = threadIdx.x & 63;
  const float4* kr = (const float4*)(k + (size_t)c * WEMB);
  float s = 0.f;
#pragma unroll
  for (int i = 0; i < 2; ++i) {
    float4 v = kr[lane + 64 * i];
    s += v.x * v.x + v.y * v.y + v.z * v.z + v.w * v.w;
  }
#pragma unroll
  for (int m = 1; m < 64; m <<= 1) s += __shfl_xor(s, m);
  if (lane == 0) g_k2[c] = s;
}

// ---------------------------------------------------------------- k -> bf16 hi/lo planes
__global__ __launch_bounds__(256) void kprep_kernel(const float* __restrict__ k) {
  const int i = blockIdx.x * 256 + threadIdx.x;    // over 262144 float4
  float4 v = ((const float4*)k)[i];
  ushort4 h, l;
  h.x = f2bf(v.x); l.x = f2bf(v.x - bf2f(h.x));
  h.y = f2bf(v.y); l.y = f2bf(v.y - bf2f(h.y));
  h.z = f2bf(v.z); l.z = f2bf(v.z - bf2f(h.z));
  h.w = f2bf(v.w); l.w = f2bf(v.w - bf2f(h.w));
  ((ushort4*)g_kh)[i] = h;
  ((ushort4*)g_kl)[i] = l;
}

// ---------------------------------------------------------------- fused VQ kernel
// Stages x (transpose + hi/lo split + x2 + prenorm) once into LDS, then scans all
// codes with k fragments streamed from L2 into registers. Sync-free main loop.

#define LOADB(BH, BL, KSV)                                                  \
  {                                                                         \
    _Pragma("unroll")                                                       \
    for (int nt = 0; nt < 4; ++nt) {                                        \
      const size_t bidx = ((size_t)(cb + nt * 16 + i16)) * WEMB             \
                          + (size_t)((KSV) * 32 + g * 8);                   \
      BH[nt] = *(const short8*)&g_kh[bidx];                                 \
      BL[nt] = *(const short8*)&g_kl[bidx];                                 \
    }                                                                       \
  }

#define COMPUTE(KSV, BH, BL)                                                \
  {                                                                         \
    short8 ah[4], al[4];                                                    \
    _Pragma("unroll")                                                       \
    for (int mt = 0; mt < 4; ++mt) {                                        \
      const int abase = (mt * 16 + i16) * ROWSTRIDE + (KSV) * 64 + g * 8;   \
      ah[mt] = *(const short8*)&x_s[abase];                                 \
      al[mt] = *(const short8*)&x_s[abase + 32];                            \
    }                                                                       \
    _Pragma("unroll")                                                       \
    for (int nt = 0; nt < 4; ++nt)                                          \
      _Pragma("unroll")                                                     \
      for (int mt = 0; mt < 4; ++mt)                                        \
        acc[mt][nt] = __builtin_amdgcn_mfma_f32_16x16x32_bf16(ah[mt], BH[nt], acc[mt][nt], 0, 0, 0); \
    _Pragma("unroll")                                                       \
    for (int nt = 0; nt < 4; ++nt)                                          \
      _Pragma("unroll")                                                     \
      for (int mt = 0; mt < 4; ++mt)                                        \
        acc[mt][nt] = __builtin_amdgcn_mfma_f32_16x16x32_bf16(ah[mt], BL[nt], acc[mt][nt], 0, 0, 0); \
    _Pragma("unroll")                                                       \
    for (int nt = 0; nt < 4; ++nt)                                          \
      _Pragma("unroll")                                                     \
      for (int mt = 0; mt < 4; ++mt)                                        \
        acc[mt][nt] = __builtin_amdgcn_mfma_f32_16x16x32_bf16(al[mt], BH[nt], acc[mt][nt], 0, 0, 0); \
  }

__global__ __launch_bounds__(512, 2) void vq_mfma(const float* __restrict__ x) {
  __shared__ short  x_s[R * ROWSTRIDE];    // 132096 B
  __shared__ float  cand_d1[8][R], cand_d2[8][R];
  __shared__ int    cand_i[8][R];
  __shared__ float  px2[8][R];
  __shared__ float  x2s[R];
  __shared__ float  rd1[R], rd2[R];
  __shared__ int    ri1[R];
  __shared__ double pnred[16];

  const int tid  = threadIdx.x;
  const int wv   = tid >> 6, lane = tid & 63;
  const int g    = lane >> 4, i16 = lane & 15;
  const int rows0 = blockIdx.x * R;
  const int n = rows0 >> 13, t0 = rows0 & (TLEN - 1);

  // ---- staging: transpose [w][t] -> LDS [t][ks][plane][w32], + x2 + prenorm ----
  double s = 0.0, s2 = 0.0;
  float px = 0.f;
  for (int j = 0; j < 64; ++j) {
    const int w = wv + 8 * j;                               // wave covers 64 w's
    const float v = x[((size_t)(n * WEMB + w)) * TLEN + (size_t)(t0 + lane)];
    const unsigned short h  = f2bf(v);
    const unsigned short lo = f2bf(v - bf2f(h));
    x_s[lane * ROWSTRIDE + (w >> 5) * 64 + (w & 31)]      = (short)h;
    x_s[lane * ROWSTRIDE + (w >> 5) * 64 + 32 + (w & 31)] = (short)lo;
    px = fmaf(v, v, px);
    s += (double)v; s2 += (double)v * (double)v;
  }
  px2[wv][lane] = px;
#pragma unroll
  for (int m = 1; m < 64; m <<= 1) { s += __shfl_xor(s, m); s2 += __shfl_xor(s2, m); }
  if (lane == 0) { pnred[wv] = s; pnred[8 + wv] = s2; }
  if (tid < R) { rd1[tid] = 3.4e38f; rd2[tid] = 3.4e38f; ri1[tid] = 0; }
  __syncthreads();
  if (tid < R) {
    float t = 0.f;
#pragma unroll
    for (int w8 = 0; w8 < 8; ++w8) t += px2[w8][tid];
    x2s[tid] = t;
  }
  if (tid == 0) {
    double a = 0, b = 0;
#pragma unroll
    for (int w8 = 0; w8 < 8; ++w8) { a += pnred[w8]; b += pnred[8 + w8]; }
    g_pnp[2 * blockIdx.x] = a; g_pnp[2 * blockIdx.x + 1] = b;
  }
  __syncthreads();

  // ---- main loop: 4 chunks x 512 codes; x LDS-resident; k from L2 to regs ----
  for (int cc = 0; cc < NCHK; ++cc) {
    const int cb = cc * CHUNK + wv * CPW;
    f32x4 acc[4][4];
#pragma unroll
    for (int mt = 0; mt < 4; ++mt)
#pragma unroll
      for (int nt = 0; nt < 4; ++nt) acc[mt][nt] = (f32x4){0.f, 0.f, 0.f, 0.f};

    short8 bhA[4], blA[4], bhB[4], blB[4];
    LOADB(bhA, blA, 0);
#pragma unroll 1
    for (int kp = 0; kp < 8; ++kp) {
      LOADB(bhB, blB, 2 * kp + 1);
      COMPUTE(2 * kp, bhA, blA);
      if (kp < 7) LOADB(bhA, blA, 2 * kp + 2);
      COMPUTE(2 * kp + 1, bhB, blB);
    }

    // epilogue: dist + wave-local top-2 over wave's 64 codes
    float k2v[4];
#pragma unroll
    for (int nt = 0; nt < 4; ++nt) k2v[nt] = g_k2[cb + nt * 16 + i16];
#pragma unroll
    for (int mt = 0; mt < 4; ++mt) {
#pragma unroll
      for (int r = 0; r < 4; ++r) {
        const int row = mt * 16 + g * 4 + r;
        const float xx = x2s[row];
        float e1 = 3.4e38f, e2 = 3.4e38f; int ei = 0x7FFFFFFF;
#pragma unroll
        for (int nt = 0; nt < 4; ++nt) {
          const float d = fmaf(-2.f, acc[mt][nt][r], xx) + k2v[nt];
          const int code = cb + nt * 16 + i16;
          if (d < e1) { e2 = e1; e1 = d; ei = code; } else e2 = fminf(e2, d);
        }
#pragma unroll
        for (int m = 1; m < 16; m <<= 1) {
          const float o1 = __shfl_xor(e1, m);
          const float o2 = __shfl_xor(e2, m);
          const int   oi = __shfl_xor(ei, m);
          if (o1 < e1)      { e2 = fminf(e1, o2); e1 = o1; ei = oi; }
          else if (o1 > e1) { e2 = fminf(e2, o1); }
          else              { e2 = e1; if (oi < ei) ei = oi; }   // tie -> margin 0 -> fixup
        }
        if (i16 == 0) { cand_d1[wv][row] = e1; cand_d2[wv][row] = e2; cand_i[wv][row] = ei; }
      }
    }
    __syncthreads();
    if (tid < R) {
      float m1 = rd1[tid], m2 = rd2[tid]; int mi = ri1[tid];
#pragma unroll
      for (int w8 = 0; w8 < 8; ++w8) {
        const float c1 = cand_d1[w8][tid], c2 = cand_d2[w8][tid];
        const int ci = cand_i[w8][tid];
        if (c1 < m1)      { m2 = fminf(m1, c2); m1 = c1; mi = ci; }
        else if (c1 > m1) { m2 = fminf(m2, c1); }
        else              { m2 = m1; if (ci < mi) mi = ci; }
      }
      rd1[tid] = m1; rd2[tid] = m2; ri1[tid] = mi;
    }
    __syncthreads();
  }

  // ---- finalize: indices, fixup list, fit partial ----
  if (tid < R) {
    const int grow = rows0 + tid;
    g_idx[grow] = ri1[tid];
    if (rd2[tid] - rd1[tid] < MARGIN_T) {
      const int pos = atomicAdd(&g_nfix, 1);
      if (pos < FIX_CAP) g_list[pos] = grow;
    }
    double fs = (double)rd1[tid];
#pragma unroll
    for (int m = 1; m < 64; m <<= 1) fs += __shfl_xor(fs, m);
    if (tid == 0) g_fitp[blockIdx.x] = fs;
  }
}

// ---------------------------------------------------------------- f64 exact argmin fixup
__global__ __launch_bounds__(256) void fix_kernel(const float* __restrict__ x,
                                                  const float* __restrict__ k) {
  __shared__ float xr[WEMB];
  __shared__ double rbd[4];
  __shared__ int    rbi[4];
  const int nfix = g_nfix < FIX_CAP ? g_nfix : FIX_CAP;
  for (int e = blockIdx.x; e < nfix; e += gridDim.x) {
    const int row = g_list[e];
    const int n = row >> 13, t = row & (TLEN - 1);
    for (int w = threadIdx.x; w < WEMB; w += 256)
      xr[w] = x[(size_t)(n * WEMB + w) * TLEN + (size_t)t];
    __syncthreads();
    double bd = 1e300; int bi = 0x7FFFFFFF;
    for (int p = 0; p < 8; ++p) {
      const int c = threadIdx.x + 256 * p;
      const float* kc = k + (size_t)c * WEMB;
      double d = 0.0;
      for (int w = 0; w < WEMB; ++w) {
        const double df = (double)xr[w] - (double)kc[w];
        d += df * df;
      }
      if (d < bd || (d == bd && c < bi)) { bd = d; bi = c; }
    }
#pragma unroll
    for (int m = 1; m < 64; m <<= 1) {
      const double od = __shfl_xor(bd, m);
      const int    oi = __shfl_xor(bi, m);
      if (od < bd || (od == bd && oi < bi)) { bd = od; bi = oi; }
    }
    const int wv = threadIdx.x >> 6, lane = threadIdx.x & 63;
    if (lane == 0) { rbd[wv] = bd; rbi[wv] = bi; }
    __syncthreads();
    if (threadIdx.x == 0) {
      double fb = rbd[0]; int fi = rbi[0];
#pragma unroll
      for (int v = 1; v < 4; ++v)
        if (rbd[v] < fb || (rbd[v] == fb && rbi[v] < fi)) { fb = rbd[v]; fi = rbi[v]; }
      g_idx[row] = fi;
    }
    __syncthreads();
  }
}

// ---------------------------------------------------------------- x_l write (f32)
__global__ __launch_bounds__(256) void xl_kernel(float* __restrict__ out) {
  const int i = blockIdx.x * 256 + threadIdx.x;
  if (i < NTROWS) out[i] = (float)g_idx[i];
}

// ---------------------------------------------------------------- x_q write (f32 gather)
__global__ __launch_bounds__(256) void xq_kernel(const float* __restrict__ k,
                                                 float* __restrict__ out) {
  const int t = blockIdx.x * 256 + threadIdx.x;
  const int w = blockIdx.y;
  const int n = blockIdx.z;
  const int idx = g_idx[n * TLEN + t];
  out[XQ_OFF + (size_t)(n * WEMB + w) * TLEN + (size_t)t] = k[(size_t)idx * WEMB + (size_t)w];
}

// ---------------------------------------------------------------- final scalars (f32)
__global__ __launch_bounds__(256) void fin_kernel(float* __restrict__ out) {
  const int tid = threadIdx.x;
  double fs = 0, s = 0, s2 = 0;
  for (int i = tid; i < 2048; i += 256) {
    fs += g_fitp[i];
    s  += g_pnp[2 * i];
    s2 += g_pnp[2 * i + 1];
  }
#pragma unroll
  for (int m = 1; m < 64; m <<= 1) {
    fs += __shfl_xor(fs, m); s += __shfl_xor(s, m); s2 += __shfl_xor(s2, m);
  }
  __shared__ double red[12];
  const int wv = tid >> 6, lane = tid & 63;
  if (lane == 0) { red[wv] = fs; red[4 + wv] = s; red[8 + wv] = s2; }
  __syncthreads();
  if (tid == 0) {
    const double F  = red[0] + red[1] + red[2] + red[3];
    const double S  = red[4] + red[5] + red[6] + red[7];
    const double S2 = red[8] + red[9] + red[10] + red[11];
    const double nel = (double)NTROWS * (double)WEMB;
    const double mean = S / nel;
    double var = S2 / nel - mean * mean;
    if (var < 0) var = 0;
    out[SC_OFF + 0] = (float)(F / nel);      // commit_loss
    out[SC_OFF + 1] = (float)(F / NTROWS);   // fit
    out[SC_OFF + 2] = (float)sqrt(var);      // prenorm
  }
}

extern "C" void kernel_launch(void* const* d_in, const int* in_sizes, int n_in,
                              void* d_out, int out_size, void* d_ws, size_t ws_size,
                              hipStream_t stream) {
  const float* x = (const float*)d_in[0];
  const float* k = (const float*)d_in[1];
  float* out = (float*)d_out;
  (void)d_ws; (void)ws_size; (void)in_sizes; (void)n_in; (void)out_size;

  hipLaunchKernelGGL(zero_kernel, dim3(1), dim3(1), 0, stream);
  hipLaunchKernelGGL(k2_kernel, dim3(KBINS / 4), dim3(256), 0, stream, k);
  hipLaunchKernelGGL(kprep_kernel, dim3(1024), dim3(256), 0, stream, k);
  hipLaunchKernelGGL(vq_mfma, dim3(NTROWS / R), dim3(512), 0, stream, x);
  hipLaunchKernelGGL(fix_kernel, dim3(2048), dim3(256), 0, stream, x, k);
  hipLaunchKernelGGL(xl_kernel, dim3(NTROWS / 256), dim3(256), 0, stream, out);
  hipLaunchKernelGGL(xq_kernel, dim3(TLEN / 256, WEMB, NBATCH), dim3(256), 0, stream, k, out);
  hipLaunchKernelGGL(fin_kernel, dim3(1), dim3(256), 0, stream, out);
}